// Round 1
// baseline (74.010 us; speedup 1.0000x reference)
//
#include <hip/hip_runtime.h>

// L0ConjunctionLayer eval forward (fuzzy-AND):
//   z[i]   = clip(sigmoid(qz[i]) * 1.2 - 0.1, 0, 1)
//   out[b,o] = prod_i (1 - (1 - x[b,i]) * z[i] * W[i,o])
// B=64, I=1024, O=1024. fp32 in/out.

#define BATCH 64
#define IN_F  1024
#define OUT_F 1024

// Main kernel: grid = (BATCH/4 batch-groups, S i-chunks), block = 256 threads.
// Thread t owns outputs o = 4*t .. 4*t+3 (float4 coalesced W loads) and the
// 4 batches of its block's batch-group -> 16 product accumulators.
// u[b,i] = (1-x)*z staged in LDS as [i][4b] so the inner loop does one
// broadcast ds_read_b128 per i.
__global__ __launch_bounds__(256) void l0_fuzzy_and_main(
        const float* __restrict__ x,
        const float* __restrict__ w,
        const float* __restrict__ qz,
        float* __restrict__ outp,   // partials (S>1) or final out (S==1)
        int L)                      // i-chunk length = IN_F / gridDim.y
{
    extern __shared__ float u_lds[];          // L*4 floats, layout [i][b]
    const int bg = blockIdx.x;                // batch group of 4
    const int s  = blockIdx.y;                // i-chunk index
    const int i0 = s * L;
    const int b0 = bg * 4;
    const int t  = threadIdx.x;

    // Stage u tile: L i's x 4 batches. z computed on the fly (4x redundant
    // per i within a block -- negligible).
    for (int idx = t; idx < L * 4; idx += 256) {
        const int ii = idx >> 2;
        const int bb = idx & 3;
        const int gi = i0 + ii;
        const float q  = qz[gi];
        const float pi = 1.0f / (1.0f + expf(-q));
        float z = fmaf(pi, 1.2f, -0.1f);
        z = fminf(fmaxf(z, 0.0f), 1.0f);
        const float xv = x[(b0 + bb) * IN_F + gi];
        u_lds[idx] = (1.0f - xv) * z;
    }
    __syncthreads();

    const int o = t * 4;
    float acc[4][4];
#pragma unroll
    for (int bb = 0; bb < 4; ++bb)
#pragma unroll
        for (int j = 0; j < 4; ++j)
            acc[bb][j] = 1.0f;

    const float* wp = w + (size_t)i0 * OUT_F + o;
#pragma unroll 4
    for (int ii = 0; ii < L; ++ii) {
        const float4 w4 = *(const float4*)wp;           // coalesced, 16B/lane
        wp += OUT_F;
        const float4 u4 = *(const float4*)(&u_lds[ii * 4]); // broadcast b128
        const float wv[4] = {w4.x, w4.y, w4.z, w4.w};
        const float uv[4] = {u4.x, u4.y, u4.z, u4.w};
#pragma unroll
        for (int bb = 0; bb < 4; ++bb)
#pragma unroll
            for (int j = 0; j < 4; ++j)
                acc[bb][j] *= fmaf(-uv[bb], wv[j], 1.0f);  // *(1 - u*w)
    }

    // partial[s][b][o] at ((s*BATCH + b)*OUT_F + o); for S==1 this is out[b][o]
    float* op = outp + (size_t)(s * BATCH + b0) * OUT_F + o;
#pragma unroll
    for (int bb = 0; bb < 4; ++bb) {
        float4 v = make_float4(acc[bb][0], acc[bb][1], acc[bb][2], acc[bb][3]);
        *(float4*)(op + (size_t)bb * OUT_F) = v;
    }
}

// Combine S partial products per output element.
__global__ __launch_bounds__(256) void l0_combine(
        const float* __restrict__ part, float* __restrict__ out, int S)
{
    const int idx = blockIdx.x * 256 + threadIdx.x;   // 0 .. BATCH*OUT_F-1
    float p = 1.0f;
    for (int s = 0; s < S; ++s)
        p *= part[(size_t)s * (BATCH * OUT_F) + idx];
    out[idx] = p;
}

extern "C" void kernel_launch(void* const* d_in, const int* in_sizes, int n_in,
                              void* d_out, int out_size, void* d_ws, size_t ws_size,
                              hipStream_t stream)
{
    const float* x  = (const float*)d_in[0];   // (64, 1024)
    const float* w  = (const float*)d_in[1];   // (1024, 1024)
    const float* qz = (const float*)d_in[2];   // (1024,)
    float* out = (float*)d_out;                // (64, 1024)

    // Split the 1024-long i-reduction into S chunks (more blocks = occupancy);
    // partials need S * 64 * 1024 * 4B of workspace. Degrade S if ws is small.
    int S = 16;
    while (S > 1 && (size_t)S * BATCH * OUT_F * sizeof(float) > ws_size)
        S >>= 1;
    const int L = IN_F / S;

    float* target = (S > 1) ? (float*)d_ws : out;
    dim3 grid(BATCH / 4, S);
    size_t lds_bytes = (size_t)L * 4 * sizeof(float);
    hipLaunchKernelGGL(l0_fuzzy_and_main, grid, dim3(256), lds_bytes, stream,
                       x, w, qz, target, L);

    if (S > 1) {
        hipLaunchKernelGGL(l0_combine, dim3((BATCH * OUT_F) / 256), dim3(256),
                           0, stream, (const float*)d_ws, out, S);
    }
}